// Round 15
// baseline (133.016 us; speedup 1.0000x reference)
//
#include <hip/hip_runtime.h>
#include <stdint.h>

// FSUMGUCell: hy = (1-fg)*ng + fg*hx
//   fg = ( [hx|x]@w_f^T + b_f + 1 ) * 0.5
//   ng =   [fg*hx|x]@w_n^T + b_n
// B=H=I=2048, K=H+I=4096. bf16 MFMA path.
//
// Round 15: FAT WAVES. r14's structure (128x64 tiles, grid 512 = 2 blocks/CU,
// 3-buf LDS, 1 barrier/step, counted vmcnt) but 2 waves/block, each owning a
// 64x64 sub-tile with 4x4 acc -> ds_read:MFMA ratio 1:2 (vs r11's 3:4).
// Evidence: DS-read volume is the binding pipe (r4/r6/r8/r12/r14 ruled out
// sync, privatization, B-source, barrier count); r9's 4x4-acc core ran 40us.
// Trade: 4 waves/CU (1/SIMD) — covered by 2-step in-flight loads + 2
// independent blocks/CU (r1's disease was the vmcnt(0) drain, absent here).

#define Hdim 2048
#define Idim 2048
#define Bdim 2048
#define Ktot 4096
#define KHALF 2048
#define NSTEP 64            // Ktot / 64
#define NSTEP2 32           // K-half boundary in BK units

typedef __bf16 bf16;
typedef __bf16 bf16x8 __attribute__((ext_vector_type(8)));
typedef float  f32x4  __attribute__((ext_vector_type(4)));

__device__ __forceinline__ void gload_lds16(const bf16* g, bf16* l) {
  __builtin_amdgcn_global_load_lds(
      (const __attribute__((address_space(1))) unsigned int*)g,
      (__attribute__((address_space(3))) unsigned int*)l,
      16, 0, 0);
}

__device__ __forceinline__ void cvt8(const float* __restrict__ src, bf16* __restrict__ dst) {
  const float4* s = (const float4*)src;
  float4 a = s[0], b = s[1];
  bf16x8 o;
  o[0]=(bf16)a.x; o[1]=(bf16)a.y; o[2]=(bf16)a.z; o[3]=(bf16)a.w;
  o[4]=(bf16)b.x; o[5]=(bf16)b.y; o[6]=(bf16)b.z; o[7]=(bf16)b.w;
  *(bf16x8*)dst = o;
}

// ---- fused prep: Wf cvt | Wn cvt | A1 = [hx|x] cvt (all f32 -> bf16 x8) ----
__global__ void prep_kernel(const float* __restrict__ w_f, const float* __restrict__ w_n,
                            const float* __restrict__ hx, const float* __restrict__ x,
                            bf16* __restrict__ Wf, bf16* __restrict__ Wn,
                            bf16* __restrict__ A1) {
  const int n8 = Hdim * Ktot / 8;
  int stride = gridDim.x * blockDim.x;
  for (int i = blockIdx.x * blockDim.x + threadIdx.x; i < 3 * n8; i += stride) {
    if (i < n8) {
      cvt8(w_f + (size_t)i * 8, Wf + (size_t)i * 8);
    } else if (i < 2 * n8) {
      int j = i - n8;
      cvt8(w_n + (size_t)j * 8, Wn + (size_t)j * 8);
    } else {
      int j = i - 2 * n8;
      int e = j * 8;
      int b = e >> 12;            // / 4096
      int k = e & (Ktot - 1);
      const float* src = (k < Hdim) ? (hx + (size_t)b * Hdim + k)
                                    : (x  + (size_t)b * Idim + (k - Hdim));
      cvt8(src, A1 + (size_t)e);
    }
  }
}

// ---- 128x64 x K=4096 GEMM, 2 waves (64x64 each, 4x4 acc), 3-buf LDS ----
// grid 512 = 16 tm x 32 tn. C[row][col] = sum_k A[row][k] * W[col][k].
// A K-halves: (Ab0,sA0) k<2048, (Ab1,sA1) k>=2048. LDS buf = [A 128x64 |
// B 64x64] bf16 = 24 KB x3 = 72 KB (2 blocks/CU). 16B-chunk XOR swizzle:
// LDS[row][c] holds global chunk c ^ (row&7), staged via inverse-swizzled
// global source (global_load_lds writes linearly); read applies same XOR.
// Staging: 128 thr x 12 loads (A 8 + B 4); 1 barrier/step; vmcnt(12) counted.
template<int EPI>
__global__ __launch_bounds__(128, 1)
void gemm_kernel(const bf16* __restrict__ Ab0, int sA0,
                 const bf16* __restrict__ Ab1, int sA1,
                 const bf16* __restrict__ W,
                 const float* __restrict__ bias,
                 const float* __restrict__ hx,   // EPI0 only
                 bf16* __restrict__ OMF,         // EPI0: write (1-fg) ; EPI1: read
                 bf16* __restrict__ A2L,         // EPI0: write bf16(fg*hx) ; EPI1: read
                 float* __restrict__ OUT)        // EPI1: write hy
{
  __shared__ bf16 lds[3][12288];   // [buf][ A:0..8191 | B:8192..12287 ] = 72 KB

  int bid  = blockIdx.x;
  int sbid = (bid & 7) * 64 + (bid >> 3);   // XCD swizzle (512%8==0, bijective)
  int tm = sbid >> 5, tn = sbid & 31;       // 16 x 32 tiles of 128x64

  int tid = threadIdx.x;
  int w = tid >> 6, lane = tid & 63;
  int wrow = w * 64;            // wave w owns rows [w*64, w*64+64), all 64 cols
  int fr = lane & 15, fq = lane >> 4;
  int swz = fr & 7;

  // staging: A 1024 + B 512 chunks/step, 128 thr -> 12 loads/thread.
  // Thread t: srow = t>>3 (0..15), dest chunk t&7, src chunk (t&7)^(srow&7).
  // A pass jj (0..7): row = jj*16 + srow ; B pass jj (0..3): row = jj*16 + srow.
  int srow = tid >> 3;
  int csrc = (tid & 7) ^ (srow & 7);

  const bf16* pA0 = Ab0 + (size_t)(tm * 128 + srow) * sA0 + csrc * 8;
  const bf16* pA1 = Ab1 + (size_t)(tm * 128 + srow) * sA1 + csrc * 8;
  const bf16* pB  = W   + (size_t)(tn * 64  + srow) * Ktot + csrc * 8;
  int lb = w * 512;                     // wave-uniform LDS base; gload adds lane*16B

#define STAGE(pbuf, t_) do {                                                   \
    const bf16* pa_ = ((t_) < NSTEP2) ? pA0 : pA1;                             \
    size_t sa_ = ((t_) < NSTEP2) ? (size_t)sA0 : (size_t)sA1;                  \
    size_t ko_ = ((t_) < NSTEP2) ? (size_t)(t_) * 64 : (size_t)((t_) - NSTEP2) * 64; \
    _Pragma("unroll")                                                          \
    for (int jj = 0; jj < 8; ++jj)                                             \
      gload_lds16(pa_ + (size_t)jj * 16 * sa_ + ko_, (pbuf) + jj * 1024 + lb); \
    _Pragma("unroll")                                                          \
    for (int jj = 0; jj < 4; ++jj)                                             \
      gload_lds16(pB + (size_t)jj * 16 * Ktot + (size_t)(t_) * 64,             \
                  (pbuf) + 8192 + jj * 1024 + lb);                             \
  } while (0)

  f32x4 acc[4][4] = {};

#define COMPUTE(pbuf) do {                                                     \
    _Pragma("unroll")                                                          \
    for (int kk = 0; kk < 2; ++kk) {                                           \
      bf16x8 af[4], bv[4];                                                     \
      int ch = ((kk * 4 + fq) ^ swz) * 8;                                      \
      _Pragma("unroll")                                                        \
      for (int m = 0; m < 4; ++m)                                              \
        af[m] = *(const bf16x8*)((pbuf) + (wrow + m * 16 + fr) * 64 + ch);     \
      _Pragma("unroll")                                                        \
      for (int n = 0; n < 4; ++n)                                              \
        bv[n] = *(const bf16x8*)((pbuf) + 8192 + (n * 16 + fr) * 64 + ch);     \
      __builtin_amdgcn_s_setprio(1);                                           \
      _Pragma("unroll")                                                        \
      for (int m = 0; m < 4; ++m)                                              \
        _Pragma("unroll")                                                      \
        for (int n = 0; n < 4; ++n)                                            \
          acc[m][n] = __builtin_amdgcn_mfma_f32_16x16x32_bf16(af[m], bv[n], acc[m][n], 0, 0, 0); \
      __builtin_amdgcn_s_setprio(0);                                           \
    }                                                                          \
  } while (0)

  bf16* p0 = &lds[0][0];
  bf16* p1 = &lds[1][0];
  bf16* p2 = &lds[2][0];

  STAGE(p0, 0);
  STAGE(p1, 1);
  #pragma unroll 1
  for (int t = 0; t < NSTEP; ++t) {
    if (t < NSTEP - 1) asm volatile("s_waitcnt vmcnt(12)" ::: "memory");
    else               asm volatile("s_waitcnt vmcnt(0)" ::: "memory");
    __builtin_amdgcn_s_barrier();        // stage(t) published; t-1 reads retired
    asm volatile("" ::: "memory");
    if (t + 2 < NSTEP) STAGE(p2, t + 2); // overwrites buffer last read at t-1
    COMPUTE(p0);
    bf16* tmp = p0; p0 = p1; p1 = p2; p2 = tmp;
  }
#undef COMPUTE
#undef STAGE

  // ---- fused epilogue. C/D layout: col = lane&15, row = (lane>>4)*4+i [m89]
  int row0 = tm * 128 + wrow + fq * 4;
  int col0 = tn * 64 + fr;
  #pragma unroll
  for (int n = 0; n < 4; ++n) {
    int gcol = col0 + n * 16;
    float bv2 = bias[gcol];
    #pragma unroll
    for (int m = 0; m < 4; ++m) {
      #pragma unroll
      for (int i = 0; i < 4; ++i) {
        int grow = row0 + m * 16 + i;
        size_t idx = (size_t)grow * Hdim + gcol;
        float v = acc[m][n][i] + bv2;
        if (EPI == 0) {
          float fg = (v + 1.0f) * 0.5f;
          OMF[idx] = (bf16)(1.0f - fg);
          A2L[idx] = (bf16)(fg * hx[idx]);
        } else {
          OUT[idx] = (float)OMF[idx] * v + (float)A2L[idx];  // (1-fg)*ng + fg*hx
        }
      }
    }
  }
}

extern "C" void kernel_launch(void* const* d_in, const int* in_sizes, int n_in,
                              void* d_out, int out_size, void* d_ws, size_t ws_size,
                              hipStream_t stream) {
  const float* x   = (const float*)d_in[0];
  const float* hx  = (const float*)d_in[1];
  const float* w_f = (const float*)d_in[2];
  const float* b_f = (const float*)d_in[3];
  const float* w_n = (const float*)d_in[4];
  const float* b_n = (const float*)d_in[5];
  float* out = (float*)d_out;

  bf16* A1  = (bf16*)d_ws;                         // [2048][4096] = 16 MB
  bf16* A2L = A1  + (size_t)Bdim * Ktot;           // [2048][2048] =  8 MB
  bf16* Wf  = A2L + (size_t)Bdim * KHALF;          // [2048][4096] = 16 MB
  bf16* Wn  = Wf  + (size_t)Hdim * Ktot;           // [2048][4096] = 16 MB
  bf16* OMF = Wn  + (size_t)Hdim * Ktot;           // [2048][2048] =  8 MB
  // ws total: 64 MB

  prep_kernel<<<2048, 256, 0, stream>>>(w_f, w_n, hx, x, Wf, Wn, A1);

  // GEMM1: A = A1 (both K-halves); fused epilogue -> OMF + A2L.
  gemm_kernel<0><<<512, 128, 0, stream>>>(A1, Ktot, A1 + KHALF, Ktot, Wf, b_f,
                                          hx, OMF, A2L, nullptr);
  // GEMM2: A = [A2L | A1 right half (x)]; fused epilogue -> hy.
  gemm_kernel<1><<<512, 128, 0, stream>>>(A2L, KHALF, A1 + Hdim, Ktot, Wn, b_n,
                                          nullptr, OMF, A2L, out);
}